// Round 4
// baseline (493.843 us; speedup 1.0000x reference)
//
#include <hip/hip_runtime.h>
#include <hip/hip_bf16.h>

// Problem constants (B=4, S=2048, H=2048, E=8, K=2)
#define T_TOK 8192
#define H_DIM 2048
#define NE 8

typedef float f32x4 __attribute__((ext_vector_type(4)));
typedef short s16x8 __attribute__((ext_vector_type(8)));

typedef __attribute__((address_space(3))) unsigned int lds_uint;
typedef __attribute__((address_space(1))) const unsigned int glob_uint;

static __device__ __forceinline__ void async_ld16(const void* g, void* l) {
    // 64 lanes x 16B: per-lane global address -> LDS (wave-uniform base + lane*16)
    __builtin_amdgcn_global_load_lds((glob_uint*)g, (lds_uint*)l, 16, 0, 0);
}

static __device__ __forceinline__ unsigned short f32_to_bf16(float f) {
    unsigned int u = __builtin_bit_cast(unsigned int, f);
    return (unsigned short)((u + 0x7FFFu + ((u >> 16) & 1u)) >> 16);
}

static __device__ __forceinline__ float bf2f(unsigned int hi16) {
    // hi16 holds a bf16 in its top 16 bits -> mask makes it an f32
    return __builtin_bit_cast(float, hi16 & 0xFFFF0000u);
}

// Pack two fp32 into two truncated bf16 (1 VALU op): result low short = bf16(lo).
static __device__ __forceinline__ unsigned int pack_bf16_trunc(float lo, float hi) {
#if __has_builtin(__builtin_amdgcn_perm)
    return __builtin_amdgcn_perm(__builtin_bit_cast(unsigned int, hi),
                                 __builtin_bit_cast(unsigned int, lo), 0x07060302u);
#else
    return (__builtin_bit_cast(unsigned int, lo) >> 16) |
           (__builtin_bit_cast(unsigned int, hi) & 0xFFFF0000u);
#endif
}

// ---------------------------------------------------------------------------
// Kernel 1: router (standalone again — fusing it with streaming conversion
// coupled its 164-VGPR budget onto the streaming blocks, R3 regression).
// 512 blocks x 16 tokens. Gate (64 KiB) staged in LDS. fp32 logits (exact),
// fused fp32->bf16 X conversion (RNE), softmax-free top-2, per-block
// aggregated list append with k-slot packed into bit 16.
// ---------------------------------------------------------------------------
__global__ __launch_bounds__(256) void router_kernel(
        const float* __restrict__ x, const float* __restrict__ gate,
        unsigned short* __restrict__ xb, float* __restrict__ logits,
        int* __restrict__ cnt, int* __restrict__ list, float* __restrict__ wl) {
    __shared__ float4 gs[NE * H_DIM / 4];  // 64 KiB
    __shared__ int aExp[32];
    __shared__ float aW[32];
    const float4* g4 = (const float4*)gate;
    for (int i = threadIdx.x; i < NE * H_DIM / 4; i += 256) gs[i] = g4[i];
    __syncthreads();

    const int wave = threadIdx.x >> 6, lane = threadIdx.x & 63;

    for (int it = 0; it < 4; ++it) {
        const int tok = wave * 4 + it;               // 0..15 within block
        const int t = blockIdx.x * 16 + tok;
        const float4* xr = (const float4*)(x + (long)t * H_DIM);
        ushort4* xw = (ushort4*)(xb + (long)t * H_DIM);
        float acc[NE];
#pragma unroll
        for (int e = 0; e < NE; ++e) acc[e] = 0.f;
#pragma unroll
        for (int i = 0; i < 8; ++i) {
            float4 xv = xr[i * 64 + lane];
            xw[i * 64 + lane] = make_ushort4(f32_to_bf16(xv.x), f32_to_bf16(xv.y),
                                             f32_to_bf16(xv.z), f32_to_bf16(xv.w));
#pragma unroll
            for (int e = 0; e < NE; ++e) {
                float4 gv = gs[e * 512 + i * 64 + lane];
                acc[e] += xv.x * gv.x + xv.y * gv.y + xv.z * gv.z + xv.w * gv.w;
            }
        }
#pragma unroll
        for (int e = 0; e < NE; ++e)
#pragma unroll
            for (int off = 32; off > 0; off >>= 1)
                acc[e] += __shfl_xor(acc[e], off, 64);

        if (lane == 0) {
            float l0 = -1e30f; int i0 = 0;
#pragma unroll
            for (int e = 0; e < NE; ++e)
                if (acc[e] > l0) { l0 = acc[e]; i0 = e; }
            float l1 = -1e30f; int i1 = 0;
#pragma unroll
            for (int e = 0; e < NE; ++e)
                if (e != i0 && acc[e] > l1) { l1 = acc[e]; i1 = e; }
            float e1v = __expf(l1 - l0);
            float inv = 1.f / (1.f + e1v);
#pragma unroll
            for (int e = 0; e < NE; ++e) logits[(long)t * NE + e] = acc[e];
            aExp[tok * 2] = i0;     aW[tok * 2] = inv;
            aExp[tok * 2 + 1] = i1; aW[tok * 2 + 1] = e1v * inv;
        }
    }
    __syncthreads();

    if (threadIdx.x < NE) {
        const int e = threadIdx.x;
        int c = 0;
#pragma unroll
        for (int k = 0; k < 32; ++k) c += (aExp[k] == e);
        if (c) {
            int pos = atomicAdd(&cnt[e], c);
            for (int k = 0; k < 32; ++k)
                if (aExp[k] == e) {
                    // pack token id (bits 0..15) and k-slot (bit 16)
                    list[e * T_TOK + pos] = (blockIdx.x * 16 + (k >> 1)) | ((k & 1) << 16);
                    wl[e * T_TOK + pos] = aW[k];
                    ++pos;
                }
        }
    }
}

// ---------------------------------------------------------------------------
// Kernel 2: grouped expert GEMM reading W directly as fp32 (no pre-convert
// pass). A (gathered bf16 X) staged via async global_load_lds; B loaded as
// fp32 dwordx4, packed to bf16 by v_perm truncation (1 op / 2 elts), written
// ds_write_b128 into the XOR-swizzled layout (phys chunk = (r<<3)|(c^(r&7))).
// XCD ordering: grp = ((idx>>6)<<3)|xcd, rt = idx&63 -> each XCD runs one
// (e,ct) group's 64 row-tiles back-to-back (1 MB fp32 B slice stays
// L2-resident) and experts interleave across XCDs (load balance).
// Epilogue: weighted partials stored bf16 to y[(tok*2+k)*H] — no atomics,
// no out zero-init.
// ---------------------------------------------------------------------------
__global__ __launch_bounds__(256, 3) void moe_gemm(
        const unsigned short* __restrict__ xb, const float* __restrict__ wf,
        const int* __restrict__ cnt, const int* __restrict__ list,
        const float* __restrict__ wl, unsigned short* __restrict__ yb) {
    __shared__ uint4 As[1024];  // 128 rows x 64 bf16 = 16 KiB
    __shared__ uint4 Bs[1024];
    __shared__ int tIdx[128];
    __shared__ float tw[128];

    const int bx  = blockIdx.x;
    const int xcd = bx & 7;           // round-robin dispatch heuristic
    const int idx = bx >> 3;          // 0..1023 sequential per XCD
    const int grp = ((idx >> 6) << 3) | xcd;  // 0..127 = e*16+ct, rt-inner
    const int rt  = idx & 63;
    const int e   = grp >> 4;
    const int ct  = grp & 15;

    const int n = cnt[e];
    const int row0 = rt << 7;
    if (row0 >= n) return;
    const int rv = min(128, n - row0);

    const int tid = threadIdx.x;
    if (tid < 128) {
        if (tid < rv) {
            tIdx[tid] = list[e * T_TOK + row0 + tid];
            tw[tid]   = wl[e * T_TOK + row0 + tid];
        } else { tIdx[tid] = 0; tw[tid] = 0.f; }
    }
    __syncthreads();

    const int wave = tid >> 6, lane = tid & 63;
    const int wm = (wave >> 1) << 6;   // 0 / 64
    const int wn = (wave & 1) << 6;    // 0 / 64
    const int quad = lane >> 4, l16 = lane & 15;

    f32x4 acc[4][4];
#pragma unroll
    for (int i = 0; i < 4; ++i)
#pragma unroll
        for (int j = 0; j < 4; ++j) acc[i][j] = (f32x4){0.f, 0.f, 0.f, 0.f};

    // A async staging: phys chunk p = i*256 + wave*64 + lane (lane-contiguous
    // LDS dst); fetch the XOR-permuted logical k-chunk per lane.
    const unsigned short* aSrc[4];
#pragma unroll
    for (int i = 0; i < 4; ++i) {
        const int p = i * 256 + wave * 64 + lane;
        const int r = p >> 3;
        const int c = (p & 7) ^ (r & 7);
        aSrc[i] = xb + (long)(tIdx[r] & 0xFFFF) * H_DIM + c * 8;
    }
    // B fp32 sources: logical chunk q = i*256 + tid -> row r=q>>3, k-chunk c=q&7
    const float4* bSrc4[4];
    int dstc[4];
    const long wbase = (long)e * H_DIM * H_DIM + (long)(ct * 128) * H_DIM;
#pragma unroll
    for (int i = 0; i < 4; ++i) {
        const int q = i * 256 + tid;
        const int r = q >> 3, c = q & 7;
        bSrc4[i] = (const float4*)(wf + wbase + (long)r * H_DIM + c * 8);
        dstc[i] = (r << 3) | (c ^ (r & 7));
    }

    for (int kt = 0; kt < H_DIM / 64; ++kt) {
        const int k0 = kt * 64;
#pragma unroll
        for (int i = 0; i < 4; ++i)
            async_ld16(aSrc[i] + k0, &As[i * 256 + wave * 64]);
        float4 b0[4], b1[4];
#pragma unroll
        for (int i = 0; i < 4; ++i) {
            b0[i] = bSrc4[i][kt * 16];
            b1[i] = bSrc4[i][kt * 16 + 1];
        }
#pragma unroll
        for (int i = 0; i < 4; ++i) {
            uint4 d;
            d.x = pack_bf16_trunc(b0[i].x, b0[i].y);
            d.y = pack_bf16_trunc(b0[i].z, b0[i].w);
            d.z = pack_bf16_trunc(b1[i].x, b1[i].y);
            d.w = pack_bf16_trunc(b1[i].z, b1[i].w);
            Bs[dstc[i]] = d;
        }
        __syncthreads();
#pragma unroll
        for (int ks = 0; ks < 2; ++ks) {
            s16x8 af[4], bfr[4];
            const int kc = ks * 4 + quad;
#pragma unroll
            for (int i = 0; i < 4; ++i) {
                int r = wm + i * 16 + l16;
                af[i] = ((const s16x8*)As)[(r << 3) | (kc ^ (r & 7))];
            }
#pragma unroll
            for (int j = 0; j < 4; ++j) {
                int d = wn + j * 16 + l16;
                bfr[j] = ((const s16x8*)Bs)[(d << 3) | (kc ^ (d & 7))];
            }
#pragma unroll
            for (int i = 0; i < 4; ++i)
#pragma unroll
                for (int j = 0; j < 4; ++j)
                    acc[i][j] = __builtin_amdgcn_mfma_f32_16x16x32_bf16(
                        af[i], bfr[j], acc[i][j], 0, 0, 0);
        }
        __syncthreads();
    }

    // Epilogue: C/D layout col = lane&15, row = quad*4 + reg.
    const int colbase = ct * 128 + wn;
#pragma unroll
    for (int i = 0; i < 4; ++i) {
        const int rbase = wm + i * 16 + quad * 4;
#pragma unroll
        for (int jr = 0; jr < 4; ++jr) {
            const int r = rbase + jr;
            if (r < rv) {
                const int entry = tIdx[r];
                const float wgt = tw[r];
                const long yrow = ((long)(entry & 0xFFFF) << 1) + (entry >> 16);
                unsigned short* yr = yb + yrow * H_DIM + colbase;
#pragma unroll
                for (int j = 0; j < 4; ++j)
                    yr[j * 16 + l16] = f32_to_bf16(acc[i][j][jr] * wgt);
            }
        }
    }
}

// ---------------------------------------------------------------------------
// Kernel 3: combine. out[t] = y[2t] + y[2t+1] (weights pre-applied).
// uint4 (16B = 8 bf16) loads; 2048 blocks x 256 threads x 4 iters x 8 floats.
// ---------------------------------------------------------------------------
__global__ __launch_bounds__(256) void combine_kernel(
        const unsigned short* __restrict__ yb, float* __restrict__ out) {
    const int g = blockIdx.x * 256 + threadIdx.x;   // 0..524287
    const uint4* y4 = (const uint4*)yb;             // 256 uint4 per token row
    float4* out4 = (float4*)out;
#pragma unroll
    for (int it = 0; it < 4; ++it) {
        const int i = g + it * 524288;  // uint4-granule index over T*H/8
        const int t = i >> 8, c = i & 255;
        uint4 a = y4[(long)(t * 2) * 256 + c];
        uint4 b = y4[(long)(t * 2 + 1) * 256 + c];
        float4 r0, r1;
        r0.x = bf2f(a.x << 16) + bf2f(b.x << 16);
        r0.y = bf2f(a.x)       + bf2f(b.x);
        r0.z = bf2f(a.y << 16) + bf2f(b.y << 16);
        r0.w = bf2f(a.y)       + bf2f(b.y);
        r1.x = bf2f(a.z << 16) + bf2f(b.z << 16);
        r1.y = bf2f(a.z)       + bf2f(b.z);
        r1.z = bf2f(a.w << 16) + bf2f(b.w << 16);
        r1.w = bf2f(a.w)       + bf2f(b.w);
        out4[(long)i * 2]     = r0;
        out4[(long)i * 2 + 1] = r1;
    }
}

// ---------------------------------------------------------------------------
extern "C" void kernel_launch(void* const* d_in, const int* in_sizes, int n_in,
                              void* d_out, int out_size, void* d_ws, size_t ws_size,
                              hipStream_t stream) {
    (void)in_sizes; (void)n_in; (void)out_size; (void)ws_size;
    const float* x    = (const float*)d_in[0];   // [T, H] fp32
    const float* gate = (const float*)d_in[1];   // [E, H] fp32
    const float* w    = (const float*)d_in[2];   // [E, H, H] fp32

    float* out    = (float*)d_out;                       // [T, H]
    float* logits = out + (size_t)T_TOK * H_DIM;         // [T, E]

    char* ws = (char*)d_ws;
    unsigned short* xb = (unsigned short*)(ws);                 // 33,554,432 B
    unsigned short* yb = (unsigned short*)(ws + 33554432);      // 67,108,864 B
    int*   cnt  = (int*)(ws + 100663296);                       // 32 B
    int*   list = (int*)(ws + 100664320);                       // 262,144 B
    float* wl   = (float*)(ws + 100926464);                     // 262,144 B
    // total ws needed: ~96.5 MB (<= R1-proven 101 MB)

    hipMemsetAsync(cnt, 0, NE * sizeof(int), stream);
    router_kernel<<<512, 256, 0, stream>>>(x, gate, xb, logits, cnt, list, wl);
    moe_gemm<<<8192, 256, 0, stream>>>(xb, w, cnt, list, wl, yb);
    combine_kernel<<<2048, 256, 0, stream>>>(yb, out);
}